// Round 5
// baseline (77.725 us; speedup 1.0000x reference)
//
#include <hip/hip_runtime.h>
#include <cstdint>

static constexpr int NBOARD = 32768;
static constexpr int NC = 361;          // 19*19
static constexpr unsigned R19 = 0x7FFFFu;
static constexpr long long C0 = 47316992LL;  // 32768*1444 (lib+alive chunk)

typedef unsigned u32x4 __attribute__((ext_vector_type(4)));  // clang vector: nontemporal-OK

// select one of 6 wave-held 64-bit words by runtime index (cndmask chain; no scratch)
__device__ __forceinline__ unsigned long long pick6(int w,
    unsigned long long a0, unsigned long long a1, unsigned long long a2,
    unsigned long long a3, unsigned long long a4, unsigned long long a5)
{
    unsigned long long r = 0ull;
    r = (w == 0) ? a0 : r;
    r = (w == 1) ? a1 : r;
    r = (w == 2) ? a2 : r;
    r = (w == 3) ? a3 : r;
    r = (w == 4) ? a4 : r;
    r = (w == 5) ? a5 : r;
    return r;
}

__global__ __launch_bounds__(256) void go_board_kernel(
    const float* __restrict__ board,        // [B,361] f32
    const unsigned* __restrict__ zst,       // [2,361] int32 (wrapped int64)
    const unsigned* __restrict__ zturn,     // [2]     int32 (wrapped)
    const int* __restrict__ cur,            // [B]     int32
    const unsigned* __restrict__ hist,      // [B,100] int32 (wrapped)
    float* __restrict__ out)                // float32: [B,4,361] ++ [B] ++ [B]
{
    const int lane = threadIdx.x & 63;
    const int b    = (int)((blockIdx.x * blockDim.x + threadIdx.x) >> 6); // one wave = one board

    const float* bd = board + (size_t)b * NC;

    // ---- phase 1: coalesced board load (streamed), ballot bitboards, per-lane zobrist XOR ----
    unsigned long long bb[6], wb[6];
    unsigned h = 0u;
    #pragma unroll
    for (int c = 0; c < 6; ++c) {
        const int idx = lane + 64 * c;
        const bool valid = (c < 5) || (idx < NC);
        float v = 0.5f;
        unsigned z0 = 0u, z1 = 0u;
        if (valid) {
            v  = __builtin_nontemporal_load(&bd[idx]);  // no reuse: don't pollute L2
            z0 = zst[idx];                               // hot (3KB, reused by all waves)
            z1 = zst[NC + idx];
        }
        const bool blk = valid && (v > 0.65f);
        const bool wht = valid && (v < 0.35f);
        bb[c] = __ballot(blk);
        wb[c] = __ballot(wht);
        if (blk) h ^= z0;
        if (wht) h ^= z1;
    }

    // wave XOR-reduce the 32-bit hash (np-ref runs on int32-wrapped inputs -> exact match)
    #pragma unroll
    for (int off = 32; off >= 1; off >>= 1) h ^= __shfl_xor(h, off);

    // ---- phase 2: re-shard to row masks. lane r: black row r; lane 32+r: white row r ----
    const int r = lane & 31;
    const bool isrow = (r < 19);
    const int colw = lane >> 5; // 0 = black rows, 1 = white rows

    unsigned long long s0 = colw ? wb[0] : bb[0];
    unsigned long long s1 = colw ? wb[1] : bb[1];
    unsigned long long s2 = colw ? wb[2] : bb[2];
    unsigned long long s3 = colw ? wb[3] : bb[3];
    unsigned long long s4 = colw ? wb[4] : bb[4];
    unsigned long long s5 = colw ? wb[5] : bb[5];

    const int start = 19 * r;          // r<=30 -> start<=570; pick6 returns 0 for w>5
    const int w0 = start >> 6;
    const int sh = start & 63;
    unsigned long long lo64 = pick6(w0,     s0, s1, s2, s3, s4, s5);
    unsigned long long hi64 = pick6(w0 + 1, s0, s1, s2, s3, s4, s5);
    unsigned long long merged = sh ? ((lo64 >> sh) | (hi64 << (64 - sh))) : lo64;
    unsigned stone = isrow ? ((unsigned)merged & R19) : 0u;

    // empty row (same value in lane r and lane 32+r); lanes with r>=19 hold 0
    unsigned other = __shfl(stone, lane ^ 32);
    unsigned empt  = isrow ? ((~(stone | other)) & R19) : 0u;

    // ---- phase 3: flood fill (both colors in parallel) ----
    // NOTE: out-of-range __shfl wraps mod 64; all wrap targets hold 0 masks, and
    // results are ANDed with `stone` (0 outside rows) -> no boundary cndmasks needed.
    unsigned eu = __shfl(empt, lane - 1);
    unsigned ed = __shfl(empt, lane + 1);
    unsigned a = stone & ((empt << 1) | (empt >> 1) | eu | ed);  // seed = stones & (nb_empty>0)

    #pragma unroll 1
    for (int it = 0; it < 45; ++it) {   // 2 dilation steps per trip = 90 total, matching fori_loop cap
        const unsigned prev = a;
        unsigned au = __shfl(a, lane - 1);
        unsigned ad = __shfl(a, lane + 1);
        a |= ((a << 1) | (a >> 1) | au | ad) & stone;
        au = __shfl(a, lane - 1);
        ad = __shfl(a, lane + 1);
        a |= ((a << 1) | (a >> 1) | au | ad) & stone;
        if (!__any(a != prev)) break;   // monotone fixpoint -> early exit is exact
    }

    // ---- phase 4: fused epilogue. Neighbor-empty masks are color-independent:
    // compute per-cell liberty count ONCE, fetch both colors' stone/alive rows,
    // emit all 4 channels per trip (6 trips, 7 bpermutes each, streamed stores).
    const size_t obase = (size_t)b * 1444;
    #pragma unroll
    for (int j = 0; j < 6; ++j) {
        const int k  = lane + 64 * j;
        const int kk = (k < NC) ? k : 0;
        const int rr = kk / 19;
        const int cc = kk - rr * 19;
        const unsigned e0  = __shfl(empt, rr);       // rows live in lanes 0..18
        const unsigned euu = __shfl(empt, rr - 1);   // rr=0 -> lane 63 -> 0
        const unsigned edd = __shfl(empt, rr + 1);   // rr=18 -> lane 19 -> 0
        const int cnt = (int)(((e0 << 1) >> cc) & 1u)
                      + (int)((e0 >> (cc + 1)) & 1u)
                      + (int)((euu >> cc) & 1u)
                      + (int)((edd >> cc) & 1u);
        const unsigned sb = __shfl(stone, rr);
        const unsigned sw = __shfl(stone, rr + 32);
        const unsigned ab = __shfl(a, rr);
        const unsigned aw = __shfl(a, rr + 32);
        if (k < NC) {
            __builtin_nontemporal_store(((sb >> cc) & 1u) ? (float)cnt : 0.0f, &out[obase + (size_t)k]);
            __builtin_nontemporal_store(((sw >> cc) & 1u) ? (float)cnt : 0.0f, &out[obase + (size_t)(361 + k)]);
            __builtin_nontemporal_store((float)((ab >> cc) & 1u),              &out[obase + (size_t)(722 + k)]);
            __builtin_nontemporal_store((float)((aw >> cc) & 1u),              &out[obase + (size_t)(1083 + k)]);
        }
    }

    // ---- phase 5: finalize hash + superko (32-bit wrapped domain, matching np-ref) ----
    const int cp = cur[b];
    const unsigned hfin = h ^ zturn[cp];

    // history: 100 u32 = 25 u32x4 (16B-aligned: b*400 bytes), lanes 0..24
    const u32x4* hb4 = (const u32x4*)(hist + (size_t)b * 100);
    bool m = false;
    if (lane < 25) {
        const u32x4 hv = __builtin_nontemporal_load(&hb4[lane]);
        m = (hv.x == hfin) | (hv.y == hfin) | (hv.z == hfin) | (hv.w == hfin);
    }
    const unsigned long long mb = __ballot(m);

    if (lane == 0) {
        out[C0 + b]          = (float)(int)hfin;     // int32 -> float32, numpy-identical rounding
        out[C0 + NBOARD + b] = (mb != 0ull) ? 1.0f : 0.0f;
    }
}

extern "C" void kernel_launch(void* const* d_in, const int* in_sizes, int n_in,
                              void* d_out, int out_size, void* d_ws, size_t ws_size,
                              hipStream_t stream) {
    const float* board     = (const float*)d_in[0];
    const unsigned* zst    = (const unsigned*)d_in[1];
    const unsigned* zturn  = (const unsigned*)d_in[2];
    const int* cur         = (const int*)d_in[3];
    const unsigned* hist   = (const unsigned*)d_in[4];
    float* out = (float*)d_out;

    // one wave per board, 4 waves per block -> 8192 blocks
    dim3 grid(NBOARD / 4), block(256);
    hipLaunchKernelGGL(go_board_kernel, grid, block, 0, stream,
                       board, zst, zturn, cur, hist, out);
}

// Round 6
// 44.966 us; speedup vs baseline: 1.7285x; 1.7285x over previous
//
#include <hip/hip_runtime.h>
#include <cstdint>

static constexpr int NBOARD = 32768;
static constexpr int NC = 361;          // 19*19
static constexpr unsigned R19 = 0x7FFFFu;
static constexpr long long C0 = 47316992LL;  // 32768*1444 (lib+alive chunk)

typedef unsigned u32x4 __attribute__((ext_vector_type(4)));

// select one of 6 wave-held 64-bit words by runtime index (cndmask chain; no scratch)
__device__ __forceinline__ unsigned long long pick6(int w,
    unsigned long long a0, unsigned long long a1, unsigned long long a2,
    unsigned long long a3, unsigned long long a4, unsigned long long a5)
{
    unsigned long long r = 0ull;
    r = (w == 0) ? a0 : r;
    r = (w == 1) ? a1 : r;
    r = (w == 2) ? a2 : r;
    r = (w == 3) ? a3 : r;
    r = (w == 4) ? a4 : r;
    r = (w == 5) ? a5 : r;
    return r;
}

__global__ __launch_bounds__(256) void go_board_kernel(
    const float* __restrict__ board,        // [B,361] f32
    const unsigned* __restrict__ zst,       // [2,361] int32 (wrapped int64)
    const unsigned* __restrict__ zturn,     // [2]     int32 (wrapped)
    const int* __restrict__ cur,            // [B]     int32
    const unsigned* __restrict__ hist,      // [B,100] int32 (wrapped)
    float* __restrict__ out)                // float32: [B,4,361] ++ [B] ++ [B]
{
    const int lane = threadIdx.x & 63;
    const int b    = (int)((blockIdx.x * blockDim.x + threadIdx.x) >> 6); // one wave = one board

    const float* bd = board + (size_t)b * NC;

    // ---- phase 1: coalesced board load, ballot bitboards, per-lane zobrist XOR ----
    unsigned long long bb[6], wb[6];
    unsigned h = 0u;
    #pragma unroll
    for (int c = 0; c < 6; ++c) {
        const int idx = lane + 64 * c;
        const bool valid = (c < 5) || (idx < NC);
        float v = 0.5f;
        unsigned z0 = 0u, z1 = 0u;
        if (valid) {
            v  = bd[idx];
            z0 = zst[idx];      // hot (3KB, reused by all waves)
            z1 = zst[NC + idx];
        }
        const bool blk = valid && (v > 0.65f);
        const bool wht = valid && (v < 0.35f);
        bb[c] = __ballot(blk);
        wb[c] = __ballot(wht);
        if (blk) h ^= z0;
        if (wht) h ^= z1;
    }

    // wave XOR-reduce the 32-bit hash (np-ref runs on int32-wrapped inputs -> exact match)
    #pragma unroll
    for (int off = 32; off >= 1; off >>= 1) h ^= __shfl_xor(h, off);

    // ---- phase 2: re-shard to row masks. lane r: black row r; lane 32+r: white row r ----
    const int r = lane & 31;
    const bool isrow = (r < 19);
    const int colw = lane >> 5; // 0 = black rows, 1 = white rows

    unsigned long long s0 = colw ? wb[0] : bb[0];
    unsigned long long s1 = colw ? wb[1] : bb[1];
    unsigned long long s2 = colw ? wb[2] : bb[2];
    unsigned long long s3 = colw ? wb[3] : bb[3];
    unsigned long long s4 = colw ? wb[4] : bb[4];
    unsigned long long s5 = colw ? wb[5] : bb[5];

    const int start = 19 * r;          // r<=30 -> start<=570; pick6 returns 0 for w>5
    const int w0 = start >> 6;
    const int sh = start & 63;
    unsigned long long lo64 = pick6(w0,     s0, s1, s2, s3, s4, s5);
    unsigned long long hi64 = pick6(w0 + 1, s0, s1, s2, s3, s4, s5);
    unsigned long long merged = sh ? ((lo64 >> sh) | (hi64 << (64 - sh))) : lo64;
    unsigned stone = isrow ? ((unsigned)merged & R19) : 0u;

    // empty row (same value in lane r and lane 32+r); lanes with r>=19 hold 0
    unsigned other = __shfl(stone, lane ^ 32);
    unsigned empt  = isrow ? ((~(stone | other)) & R19) : 0u;

    // ---- phase 3: flood fill (both colors in parallel) ----
    // NOTE: out-of-range __shfl wraps mod 64; all wrap targets hold 0 masks, and
    // results are ANDed with `stone` (0 outside rows) -> no boundary cndmasks needed.
    unsigned eu = __shfl(empt, lane - 1);
    unsigned ed = __shfl(empt, lane + 1);
    unsigned a = stone & ((empt << 1) | (empt >> 1) | eu | ed);  // seed = stones & (nb_empty>0)

    #pragma unroll 1
    for (int it = 0; it < 45; ++it) {   // 2 dilation steps per trip = 90 total, matching fori_loop cap
        const unsigned prev = a;
        unsigned au = __shfl(a, lane - 1);
        unsigned ad = __shfl(a, lane + 1);
        a |= ((a << 1) | (a >> 1) | au | ad) & stone;
        au = __shfl(a, lane - 1);
        ad = __shfl(a, lane + 1);
        a |= ((a << 1) | (a >> 1) | au | ad) & stone;
        if (!__any(a != prev)) break;   // monotone fixpoint -> early exit is exact
    }

    // ---- phase 4: fused epilogue. Neighbor-empty masks are color-independent:
    // compute per-cell liberty count ONCE, fetch both colors' stone/alive rows,
    // emit all 4 channels per trip (6 trips, 7 bpermutes each).
    const size_t obase = (size_t)b * 1444;
    #pragma unroll
    for (int j = 0; j < 6; ++j) {
        const int k  = lane + 64 * j;
        const int kk = (k < NC) ? k : 0;
        const int rr = kk / 19;
        const int cc = kk - rr * 19;
        const unsigned e0  = __shfl(empt, rr);       // rows live in lanes 0..18
        const unsigned euu = __shfl(empt, rr - 1);   // rr=0 -> lane 63 -> 0
        const unsigned edd = __shfl(empt, rr + 1);   // rr=18 -> lane 19 -> 0
        const int cnt = (int)(((e0 << 1) >> cc) & 1u)
                      + (int)((e0 >> (cc + 1)) & 1u)
                      + (int)((euu >> cc) & 1u)
                      + (int)((edd >> cc) & 1u);
        const unsigned sb = __shfl(stone, rr);
        const unsigned sw = __shfl(stone, rr + 32);
        const unsigned ab = __shfl(a, rr);
        const unsigned aw = __shfl(a, rr + 32);
        if (k < NC) {
            out[obase + (size_t)k]           = ((sb >> cc) & 1u) ? (float)cnt : 0.0f;
            out[obase + (size_t)(361 + k)]   = ((sw >> cc) & 1u) ? (float)cnt : 0.0f;
            out[obase + (size_t)(722 + k)]   = (float)((ab >> cc) & 1u);
            out[obase + (size_t)(1083 + k)]  = (float)((aw >> cc) & 1u);
        }
    }

    // ---- phase 5: finalize hash + superko (32-bit wrapped domain, matching np-ref) ----
    const int cp = cur[b];
    const unsigned hfin = h ^ zturn[cp];

    // history: 100 u32 = 25 u32x4 (16B-aligned: b*400 bytes), lanes 0..24
    const u32x4* hb4 = (const u32x4*)(hist + (size_t)b * 100);
    bool m = false;
    if (lane < 25) {
        const u32x4 hv = hb4[lane];
        m = (hv.x == hfin) | (hv.y == hfin) | (hv.z == hfin) | (hv.w == hfin);
    }
    const unsigned long long mb = __ballot(m);

    if (lane == 0) {
        out[C0 + b]          = (float)(int)hfin;     // int32 -> float32, numpy-identical rounding
        out[C0 + NBOARD + b] = (mb != 0ull) ? 1.0f : 0.0f;
    }
}

extern "C" void kernel_launch(void* const* d_in, const int* in_sizes, int n_in,
                              void* d_out, int out_size, void* d_ws, size_t ws_size,
                              hipStream_t stream) {
    const float* board     = (const float*)d_in[0];
    const unsigned* zst    = (const unsigned*)d_in[1];
    const unsigned* zturn  = (const unsigned*)d_in[2];
    const int* cur         = (const int*)d_in[3];
    const unsigned* hist   = (const unsigned*)d_in[4];
    float* out = (float*)d_out;

    // one wave per board, 4 waves per block -> 8192 blocks
    dim3 grid(NBOARD / 4), block(256);
    hipLaunchKernelGGL(go_board_kernel, grid, block, 0, stream,
                       board, zst, zturn, cur, hist, out);
}